// Round 9
// baseline (395.472 us; speedup 1.0000x reference)
//
#include <hip/hip_runtime.h>

// ---------------- problem constants ----------------
#define T_TOK 2048
#define NEXP  8
#define H_DIM 1024
#define I_DIM 4096

#define N13  (2*I_DIM)     // 8192
#define N2   (H_DIM)
#define NG13 8
#define NG2  32

#define KSPLIT2 4
#define KLEN2 (I_DIM/KSPLIT2)   // 1024
#define BK   64

#define MAXT1 24           // max 256-row tiles over all experts (16+8 worst)

typedef __bf16 bf16x8 __attribute__((ext_vector_type(8)));
typedef float  f32x4  __attribute__((ext_vector_type(4)));

#define GLD_LDS(g, l) \
  __builtin_amdgcn_global_load_lds((const __attribute__((address_space(1))) void*)(g), \
                                   (__attribute__((address_space(3))) void*)(l), 16, 0, 0)

// ---------------- workspace layout (bytes) ----------------
#define WS_OFFS   64
#define WS_PLIST  (WS_OFFS  + 64)
#define WS_PW     (WS_PLIST + 2*T_TOK*4)
#define WS_WL     65792
#define WS_NTS    66176
#define WS_SPOS   66432
#define PAIR_PAD  (2*T_TOK + 128)
#define WS_XG     131072
#define WS_ACT    (WS_XG  + PAIR_PAD*H_DIM*2)
#define WS_B1T    (WS_ACT + (size_t)PAIR_PAD*I_DIM*2)
#define WS_W2T    (WS_B1T + (size_t)NEXP*N13*H_DIM*2)
// outp (gemm2 partials, f32, KSPLIT2 x PAIR_PAD x H) ALIASES B1T.

// =====================================================================
// Fused routing: top-2 + count + scan + scatter + 256-row worklist.
// =====================================================================
__global__ __launch_bounds__(512) void k_route(
    const float* __restrict__ logits,
    int* __restrict__ offs,
    int* __restrict__ plist, float* __restrict__ pw,
    int* __restrict__ spos,
    int* __restrict__ wl, int* __restrict__ nts) {

    __shared__ int cnt[NEXP], cur[NEXP];
    __shared__ short se[2*T_TOK];
    __shared__ float swt[2*T_TOK];

    const int tid = threadIdx.x;
    if (tid < NEXP) cnt[tid] = 0;
    __syncthreads();

    for (int t = tid; t < T_TOK; t += 512) {
        float l[NEXP];
        #pragma unroll
        for (int e = 0; e < NEXP; e++) l[e] = logits[t * NEXP + e];
        int i0 = 0; float b0 = l[0];
        #pragma unroll
        for (int e = 1; e < NEXP; e++) if (l[e] > b0) { b0 = l[e]; i0 = e; }
        int i1 = -1; float b1 = -1e30f;
        #pragma unroll
        for (int e = 0; e < NEXP; e++) if (e != i0 && l[e] > b1) { b1 = l[e]; i1 = e; }
        float w1 = 1.f / (1.f + __expf(b0 - b1));
        float w0 = 1.f - w1;
        se[2*t] = (short)i0; se[2*t+1] = (short)i1;
        swt[2*t] = w0; swt[2*t+1] = w1;
        atomicAdd(&cnt[i0], 1);
        atomicAdd(&cnt[i1], 1);
    }
    __syncthreads();

    if (tid == 0) {
        int s = 0;
        for (int e = 0; e < NEXP; e++) { offs[e] = s; cur[e] = s; s += cnt[e]; }
        offs[NEXP] = s;
        int n = 0;
        for (int e = 0; e < NEXP; e++)
            for (int mt = 0; mt * 256 < cnt[e]; mt++) wl[n++] = (e << 8) | mt;
        nts[0] = n;
    }
    __syncthreads();

    for (int t = tid; t < T_TOK; t += 512) {
        #pragma unroll
        for (int s = 0; s < 2; s++) {
            int e = se[2*t+s];
            int pos = atomicAdd(&cur[e], 1);
            plist[pos] = t;
            pw[pos] = swt[2*t+s];
            spos[2*t+s] = pos;
        }
    }
}

__global__ void k_gather(const float* __restrict__ x, const int* __restrict__ plist,
                         __bf16* __restrict__ xg) {
    int p = blockIdx.x;
    int t = plist[p];
    int i = threadIdx.x;
    const f32x4* src = reinterpret_cast<const f32x4*>(x + (size_t)t * H_DIM);
    f32x4 v0 = src[i*2], v1 = src[i*2+1];
    __align__(16) __bf16 tb[8];
    #pragma unroll
    for (int j = 0; j < 4; j++) { tb[j] = (__bf16)v0[j]; tb[4+j] = (__bf16)v1[j]; }
    *reinterpret_cast<f32x4*>(xg + (size_t)p * H_DIM + i*8) = *reinterpret_cast<f32x4*>(tb);
}

// =====================================================================
// Transpose-dequant: int4 [K/8][N] -> bf16 B^T [R][K]
// =====================================================================
template<bool INTERLEAVE>
__global__ __launch_bounds__(256) void k_dequant(
    const int* __restrict__ q, const float* __restrict__ s, const int* __restrict__ g,
    __bf16* __restrict__ outw, int R, int K, int N, int NG) {

    const int e  = blockIdx.z;
    const int r0 = blockIdx.x * 64;
    const int k0 = blockIdx.y * 128;
    const int*   qe = q + (size_t)e * (K/8) * N;
    const float* se = s + (size_t)e * NG * N;
    const int*   ge = g + (size_t)e * K + k0;
    __bf16*      oe = outw + (size_t)e * R * K;

    __shared__ __align__(16) __bf16 tile[64][128];

    const int t  = threadIdx.x;
    const int rl = t & 63, kq = t >> 6;
    const int r  = r0 + rl;
    const int S  = INTERLEAVE ? (((r >> 4) << 3) + (r & 7) + (((r >> 3) & 1) ? (N >> 1) : 0))
                              : r;
    #pragma unroll
    for (int jj = 0; jj < 4; jj++) {
        int kp = kq + jj*4;
        int qv = qe[(size_t)(k0/8 + kp) * N + S];
        __align__(16) __bf16 tmp[8];
        #pragma unroll
        for (int j2 = 0; j2 < 8; j2++) {
            float sc = se[(size_t)ge[kp*8 + j2] * N + S];
            tmp[j2] = (__bf16)((float)(((qv >> (4*j2)) & 15) - 8) * sc);
        }
        int c = kp ^ (rl & 15);
        *reinterpret_cast<f32x4*>(&tile[rl][c*8]) = *reinterpret_cast<f32x4*>(tmp);
    }
    __syncthreads();
    #pragma unroll
    for (int i = 0; i < 4; i++) {
        int sidx = t + i*256;
        int row = sidx >> 4, ch = sidx & 15;
        int cs = ch ^ (row & 15);
        *reinterpret_cast<f32x4*>(oe + (size_t)(r0+row)*K + k0 + ch*8)
            = *reinterpret_cast<const f32x4*>(&tile[row][cs*8]);
    }
}

// =====================================================================
// 256x256 8-wave GEMMs with READ-AHEAD pipeline (m201 phase order):
// region p = { lgkm0; MFMA(frags read in region p-1); stage; [vm gate];
//              issue ds_reads for phase p+1; barrier }.
// Gate ledger (2 gloads per stage call, 4 stage calls/kt):
//   G1 (region q0): vmcnt(2) drains kt-1's khalf1 A+B (outstanding 6->2);
//                   last kt: vmcnt(0) (only 4 outstanding, no new stages).
//   G2 (region q2): vmcnt(2) drains kt's khalf0 A+B of nxt parity.
// Every ds_read issue is >=1 barrier AFTER the gate confirming its data
// (cross-wave safe: all waves passed their own gate at that barrier).
// WAR: reads of a slot are lgkm-drained >=1 barrier before its re-stage.
// =====================================================================
#define VM4 asm volatile("s_waitcnt vmcnt(4)" ::: "memory")
#define VM2 asm volatile("s_waitcnt vmcnt(2)" ::: "memory")
#define VM0 asm volatile("s_waitcnt vmcnt(0)" ::: "memory")
#define LGK0 { asm volatile("s_waitcnt lgkmcnt(0)" ::: "memory"); __builtin_amdgcn_sched_barrier(0); }
#define BARRIER  { __builtin_amdgcn_s_barrier(); __builtin_amdgcn_sched_barrier(0); }
#define SCHEDFENCE __builtin_amdgcn_sched_barrier(0)

#define MFMA16(ACC, A, B) \
    { _Pragma("unroll") \
      for (int j = 0; j < 4; j++) \
        _Pragma("unroll") \
        for (int i = 0; i < 4; i++) \
            ACC[i][j] = __builtin_amdgcn_mfma_f32_16x16x32_bf16(A[i], B[j], ACC[i][j], 0, 0, 0); }

#define READ_B(DST, BASE, KH) \
    { _Pragma("unroll") \
      for (int j = 0; j < 4; j++) \
        DST[j] = *reinterpret_cast<const bf16x8*>(&(BASE)[(KH)*8192 + (wc + 16*j + lrow)*32 + cq*8]); }

#define READ_A(DST, BASE, KH, RO) \
    { _Pragma("unroll") \
      for (int i = 0; i < 4; i++) \
        DST[i] = *reinterpret_cast<const bf16x8*>(&(BASE)[(KH)*8192 + (wr + (RO) + 16*i + lrow)*32 + cq*8]); }

// ---------------- gemm1: 256x256 tile, K=1024 ----------------
__global__ __launch_bounds__(512) void k_gemm1(
    const __bf16* __restrict__ xg,
    const __bf16* __restrict__ B1t,
    const int*    __restrict__ offs,
    const float*  __restrict__ pw,
    const int*    __restrict__ wl,
    const int*    __restrict__ nts,
    __bf16*       __restrict__ act) {

    const int ti = blockIdx.x >> 5;        // 32 nb per tile
    if (ti >= nts[0]) return;
    const int nb = blockIdx.x & 31;
    const int w  = wl[ti];
    const int e  = w >> 8, mt = w & 255;
    const int m0 = offs[e] + mt * 256;
    const int mcount = min(offs[e+1] - m0, 256);
    const int n0r = nb * 256;

    __shared__ __align__(16) __bf16 AsF[2*2*8192];   // [parity][khalf][256*32]
    __shared__ __align__(16) __bf16 BsF[2*2*8192];
    __shared__ float wts[256];

    const int tid = threadIdx.x;
    const int wv = tid >> 6, lane = tid & 63;
    const int lrow = lane & 15, quad = lane >> 4;
    const int wr = (wv >> 2) * 128;      // wave M-offset
    const int wc = (wv & 3) * 64;        // wave N-offset
    const int cq = quad ^ ((lrow >> 1) & 3);

    for (int m = tid; m < 256; m += 512)
        wts[m] = (m < mcount) ? pw[m0 + m] : 0.f;

    const __bf16* Abase = xg  + (size_t)m0 * H_DIM;
    const __bf16* Bbase = B1t + ((size_t)e * N13 + n0r) * H_DIM;

    f32x4 accL[4][4], accH[4][4];
    #pragma unroll
    for (int i = 0; i < 4; i++)
        #pragma unroll
        for (int j = 0; j < 4; j++) { accL[i][j] = (f32x4)(0.f); accH[i][j] = (f32x4)(0.f); }

    auto stageA = [&](int prt, int h2, int kt) {
        const __bf16* g = Abase + kt * BK + h2 * 32;
        __bf16* d = AsF + prt * 16384 + h2 * 8192;
        #pragma unroll
        for (int q2 = 0; q2 < 2; q2++) {
            int row = (tid >> 2) + q2 * 128;
            int gch = (tid & 3) ^ ((row >> 1) & 3);
            int rowc = min(row, mcount - 1);
            GLD_LDS(g + (size_t)rowc * H_DIM + gch * 8, d + tid * 8 + q2 * 4096);
        }
    };
    auto stageB = [&](int prt, int h2, int kt) {
        const __bf16* g = Bbase + kt * BK + h2 * 32;
        __bf16* d = BsF + prt * 16384 + h2 * 8192;
        #pragma unroll
        for (int q2 = 0; q2 < 2; q2++) {
            int row = (tid >> 2) + q2 * 128;
            int gch = (tid & 3) ^ ((row >> 1) & 3);
            GLD_LDS(g + (size_t)row * H_DIM + gch * 8, d + tid * 8 + q2 * 4096);
        }
    };

    // prologue: stage tile0 fully; confirm khalf0; barrier; pre-read phase0
    stageA(0, 0, 0); stageB(0, 0, 0); stageA(0, 1, 0); stageB(0, 1, 0);
    VM4;
    BARRIER;
    bf16x8 bbA[4], bbB[4], aC[4], aN[4];
    READ_B(bbA, BsF, 0);
    READ_A(aC,  AsF, 0, 0);
    SCHEDFENCE;

    const int NT = H_DIM / BK;   // 16
    for (int kt = 0; kt < NT; kt++) {
        const int prt = kt & 1, nxt = prt ^ 1;
        const bool st = (kt + 1 < NT);
        const __bf16* Ab  = AsF + prt * 16384;
        const __bf16* Bb  = BsF + prt * 16384;
        const __bf16* Abn = AsF + nxt * 16384;
        const __bf16* Bbn = BsF + nxt * 16384;

        // region q0: MFMA lo x khalf0; gate khalf1(prt); read a_hi khalf0
        LGK0;
        __builtin_amdgcn_s_setprio(1);
        MFMA16(accL, aC, bbA);
        __builtin_amdgcn_s_setprio(0);
        SCHEDFENCE;
        if (st) { stageA(nxt, 0, kt + 1); VM2; } else { VM0; }
        READ_A(aN, Ab, 0, 64);
        BARRIER;

        // region q1: MFMA hi x khalf0; read bb+a_lo khalf1
        LGK0;
        __builtin_amdgcn_s_setprio(1);
        MFMA16(accH, aN, bbA);
        __builtin_amdgcn_s_setprio(0);
        SCHEDFENCE;
        if (st) stageB(nxt, 0, kt + 1);
        READ_B(bbB, Bb, 1);
        READ_A(aC,  Ab, 1, 0);
        BARRIER;

        // region q2: MFMA lo x khalf1; gate khalf0(nxt); read a_hi khalf1
        LGK0;
        __builtin_amdgcn_s_setprio(1);
        MFMA16(accL, aC, bbB);
        __builtin_amdgcn_s_setprio(0);
        SCHEDFENCE;
        if (st) { stageA(nxt, 1, kt + 1); VM2; }
        READ_A(aN, Ab, 1, 64);
        BARRIER;

        // region q3: MFMA hi x khalf1; read bb+a_lo khalf0 of nxt
        LGK0;
        __builtin_amdgcn_s_setprio(1);
        MFMA16(accH, aN, bbB);
        __builtin_amdgcn_s_setprio(0);
        SCHEDFENCE;
        if (st) {
            stageB(nxt, 1, kt + 1);
            READ_B(bbA, Bbn, 0);
            READ_A(aC,  Abn, 0, 0);
            BARRIER;
        }
    }

    // epilogue: lrow<8 = gate, lrow>=8 = up of same logical col (shfl pair)
    #pragma unroll
    for (int j = 0; j < 4; j++) {
        const int c0 = ((n0r + wc + 16*j) >> 1);
        #pragma unroll
        for (int i = 0; i < 8; i++)
            #pragma unroll
            for (int rr = 0; rr < 4; rr++) {
                float v = (i < 4) ? accL[i][j][rr] : accH[i-4][j][rr];
                float partner = __shfl_xor(v, 8, 64);
                int m = wr + 16*i + quad*4 + rr;
                if (lrow < 8 && m < mcount) {
                    float gg = v, uu = partner;
                    float a = (gg / (1.f + __expf(-gg))) * uu * wts[m];
                    act[(size_t)(m0 + m) * I_DIM + c0 + lrow] = (__bf16)a;
                }
            }
    }
}

// ---------------- gemm2: 256x256 tile, K=1024 (KSPLIT2=4), NO atomics ----
__global__ __launch_bounds__(512) void k_gemm2(
    const __bf16* __restrict__ act,
    const __bf16* __restrict__ W2t,
    const int*    __restrict__ offs,
    const int*    __restrict__ wl,
    const int*    __restrict__ nts,
    float*        __restrict__ outp) {

    const int ti = blockIdx.x >> 4;        // 4 nb * 4 ks per tile
    if (ti >= nts[0]) return;
    const int nb = (blockIdx.x >> 2) & 3;
    const int ks = blockIdx.x & 3;
    const int w  = wl[ti];
    const int e  = w >> 8, mt = w & 255;
    const int m0 = offs[e] + mt * 256;
    const int mcount = min(offs[e+1] - m0, 256);
    const int n0 = nb * 256;
    const int kz = ks * KLEN2;

    __shared__ __align__(16) __bf16 AsF[2*2*8192];   // [parity][khalf][256*32]
    __shared__ __align__(16) __bf16 BsF[2*2*8192];

    const int tid = threadIdx.x;
    const int wv = tid >> 6, lane = tid & 63;
    const int lrow = lane & 15, quad = lane >> 4;
    const int wr = (wv >> 2) * 128;
    const int wc = (wv & 3) * 64;
    const int cq = quad ^ ((lrow >> 1) & 3);

    const __bf16* Abase = act + (size_t)m0 * I_DIM + kz;
    const __bf16* Bbase = W2t + ((size_t)e * N2 + n0) * I_DIM + kz;

    f32x4 accL[4][4], accH[4][4];
    #pragma unroll
    for (int i = 0; i < 4; i++)
        #pragma unroll
        for (int j = 0; j < 4; j++) { accL[i][j] = (f32x4)(0.f); accH[i][j] = (f32x4)(0.f); }

    auto stageA = [&](int prt, int h2, int kt) {
        const __bf16* g = Abase + kt * BK + h2 * 32;
        __bf16* d = AsF + prt * 16384 + h2 * 8192;
        #pragma unroll
        for (int q2 = 0; q2 < 2; q2++) {
            int row = (tid >> 2) + q2 * 128;
            int gch = (tid & 3) ^ ((row >> 1) & 3);
            int rowc = min(row, mcount - 1);
            GLD_LDS(g + (size_t)rowc * I_DIM + gch * 8, d + tid * 8 + q2 * 4096);
        }
    };
    auto stageB = [&](int prt, int h2, int kt) {
        const __bf16* g = Bbase + kt * BK + h2 * 32;
        __bf16* d = BsF + prt * 16384 + h2 * 8192;
        #pragma unroll
        for (int q2 = 0; q2 < 2; q2++) {
            int row = (tid >> 2) + q2 * 128;
            int gch = (tid & 3) ^ ((row >> 1) & 3);
            GLD_LDS(g + (size_t)row * I_DIM + gch * 8, d + tid * 8 + q2 * 4096);
        }
    };

    stageA(0, 0, 0); stageB(0, 0, 0); stageA(0, 1, 0); stageB(0, 1, 0);
    VM4;
    BARRIER;
    bf16x8 bbA[4], bbB[4], aC[4], aN[4];
    READ_B(bbA, BsF, 0);
    READ_A(aC,  AsF, 0, 0);
    SCHEDFENCE;

    const int NT = KLEN2 / BK;   // 16
    for (int kt = 0; kt < NT; kt++) {
        const int prt = kt & 1, nxt = prt ^ 1;
        const bool st = (kt + 1 < NT);
        const __bf16* Ab  = AsF + prt * 16384;
        const __bf16* Bb  = BsF + prt * 16384;
        const __bf16* Abn = AsF + nxt * 16384;
        const __bf16* Bbn = BsF + nxt * 16384;

        LGK0;
        __builtin_amdgcn_s_setprio(1);
        MFMA16(accL, aC, bbA);
        __builtin_amdgcn_s_setprio(0);
        SCHEDFENCE;
        if (st) { stageA(nxt, 0, kt + 1); VM2; } else { VM0; }
        READ_A(aN, Ab, 0, 64);
        BARRIER;

        LGK0;
        __builtin_amdgcn_s_setprio(1);
        MFMA16(accH, aN, bbA);
        __builtin_amdgcn_s_setprio(0);
        SCHEDFENCE;
        if (st) stageB(nxt, 0, kt + 1);
        READ_B(bbB, Bb, 1);
        READ_A(aC,  Ab, 1, 0);
        BARRIER;

        LGK0;
        __builtin_amdgcn_s_setprio(1);
        MFMA16(accL, aC, bbB);
        __builtin_amdgcn_s_setprio(0);
        SCHEDFENCE;
        if (st) { stageA(nxt, 1, kt + 1); VM2; }
        READ_A(aN, Ab, 1, 64);
        BARRIER;

        LGK0;
        __builtin_amdgcn_s_setprio(1);
        MFMA16(accH, aN, bbB);
        __builtin_amdgcn_s_setprio(0);
        SCHEDFENCE;
        if (st) {
            stageB(nxt, 1, kt + 1);
            READ_B(bbA, Bbn, 0);
            READ_A(aC,  Abn, 0, 0);
            BARRIER;
        }
    }

    // plain stores to pair-slot partial buffer (no conflicts: unique (ks,p,h))
    float* op = outp + ((size_t)ks * PAIR_PAD + m0) * N2;
    #pragma unroll
    for (int j = 0; j < 4; j++) {
        int h = n0 + wc + 16*j + lrow;
        #pragma unroll
        for (int i = 0; i < 8; i++)
            #pragma unroll
            for (int rr = 0; rr < 4; rr++) {
                int m = wr + 16*i + quad*4 + rr;
                float v = (i < 4) ? accL[i][j][rr] : accH[i-4][j][rr];
                if (m < mcount)
                    op[(size_t)m * N2 + h] = v;
            }
    }
}

// ---------------- final reduce: out[t] = sum over 2 slots x KSPLIT2 ----
__global__ __launch_bounds__(256) void k_reduce(
    const float* __restrict__ outp, const int* __restrict__ spos,
    float* __restrict__ out) {
    const int t  = blockIdx.x;
    const int h4 = threadIdx.x;            // 256 threads x float4 = 1024 h
    const int p0 = spos[2*t], p1 = spos[2*t+1];
    const f32x4* r0 = reinterpret_cast<const f32x4*>(outp + (size_t)p0 * H_DIM) + h4;
    const f32x4* r1 = reinterpret_cast<const f32x4*>(outp + (size_t)p1 * H_DIM) + h4;
    f32x4 acc = (f32x4)(0.f);
    #pragma unroll
    for (int ks = 0; ks < KSPLIT2; ks++) {
        size_t off = (size_t)ks * (PAIR_PAD * (H_DIM/4));
        acc += r0[off] + r1[off];
    }
    reinterpret_cast<f32x4*>(out + (size_t)t * H_DIM)[h4] = acc;
}

// =====================================================================
extern "C" void kernel_launch(void* const* d_in, const int* in_sizes, int n_in,
                              void* d_out, int out_size, void* d_ws, size_t ws_size,
                              hipStream_t stream) {
    const float* x      = (const float*)d_in[0];
    const float* logits = (const float*)d_in[1];
    const int*   w13q   = (const int*)  d_in[2];
    const int*   w2q    = (const int*)  d_in[3];
    const float* w13s   = (const float*)d_in[4];
    const float* w2s    = (const float*)d_in[5];
    const int*   g13    = (const int*)  d_in[6];
    const int*   g2     = (const int*)  d_in[7];

    char* ws = (char*)d_ws;
    int*    offs   = (int*)   (ws + WS_OFFS);
    int*    plist  = (int*)   (ws + WS_PLIST);
    float*  pw     = (float*) (ws + WS_PW);
    int*    wl     = (int*)   (ws + WS_WL);
    int*    nts    = (int*)   (ws + WS_NTS);
    int*    spos   = (int*)   (ws + WS_SPOS);
    __bf16* xg     = (__bf16*)(ws + WS_XG);
    __bf16* act    = (__bf16*)(ws + WS_ACT);
    __bf16* B1t    = (__bf16*)(ws + WS_B1T);
    __bf16* W2t    = (__bf16*)(ws + WS_W2T);
    float*  outp   = (float*) (ws + WS_B1T);   // aliases B1t (dead after gemm1)
    float*  out    = (float*) d_out;

    k_dequant<true ><<<dim3(N13/64, H_DIM/128, NEXP), 256, 0, stream>>>(
        w13q, w13s, g13, B1t, N13, H_DIM, N13, NG13);
    k_dequant<false><<<dim3(N2/64,  I_DIM/128, NEXP), 256, 0, stream>>>(
        w2q,  w2s,  g2,  W2t, N2,  I_DIM, N2,  NG2);

    k_route <<<1, 512, 0, stream>>>(logits, offs, plist, pw, spos, wl, nts);
    k_gather<<<2*T_TOK, 128, 0, stream>>>(x, plist, xg);

    // worklist-driven grids: 256-row tiles x fan-out
    k_gemm1<<<MAXT1 * 32, 512, 0, stream>>>(xg, B1t, offs, pw, wl, nts, act);
    k_gemm2<<<MAXT1 * 16, 512, 0, stream>>>(act, W2t, offs, wl, nts, outp);
    k_reduce<<<T_TOK, 256, 0, stream>>>(outp, spos, out);
}

// Round 10
// 355.183 us; speedup vs baseline: 1.1134x; 1.1134x over previous
//
#include <hip/hip_runtime.h>

// ---------------- problem constants ----------------
#define T_TOK 2048
#define NEXP  8
#define H_DIM 1024
#define I_DIM 4096

#define N13  (2*I_DIM)     // 8192
#define N2   (H_DIM)
#define NG13 8
#define NG2  32

#define KSPLIT2 4
#define KLEN2 (I_DIM/KSPLIT2)   // 1024
#define BK   64

#define MAXT2 40           // max 128-row tiles over all experts (32+7 worst)

#define DQ1_BLOCKS ((N13/64)*(H_DIM/128)*NEXP)   // 8192
#define DQ2_BLOCKS ((N2/64)*(I_DIM/128)*NEXP)    // 4096

typedef __bf16 bf16x8 __attribute__((ext_vector_type(8)));
typedef float  f32x4  __attribute__((ext_vector_type(4)));

#define GLD_LDS(g, l) \
  __builtin_amdgcn_global_load_lds((const __attribute__((address_space(1))) void*)(g), \
                                   (__attribute__((address_space(3))) void*)(l), 16, 0, 0)

// ---------------- workspace layout (bytes) ----------------
#define WS_OFFS   64
#define WS_PLIST  (WS_OFFS  + 64)
#define WS_PW     (WS_PLIST + 2*T_TOK*4)
#define WS_WL     65792
#define WS_NTS    66176
#define WS_SPOS   66432
#define PAIR_PAD  (2*T_TOK + 128)
#define WS_XG     131072
#define WS_ACT    (WS_XG  + PAIR_PAD*H_DIM*2)
#define WS_B1T    (WS_ACT + (size_t)PAIR_PAD*I_DIM*2)
#define WS_W2T    (WS_B1T + (size_t)NEXP*N13*H_DIM*2)
// outp (gemm2 partials, f32, KSPLIT2 x PAIR_PAD x H) ALIASES B1T:
// B1T is dead once gemm1 completes; gemm2/reduce run strictly after.

// =====================================================================
// k_prep: ONE launch = route (block 0) + dequant13 + dequant2.
// Route's ~5us single-block serial time hides under 12k dequant blocks;
// saves two launch gaps vs separate kernels.
// =====================================================================
template<bool INTERLEAVE>
__device__ __forceinline__ void dequant_tile(
    const int* __restrict__ q, const float* __restrict__ s,
    const int* __restrict__ g, __bf16* __restrict__ outw,
    int R, int K, int N, int NG, int e, int r0, int k0, char* smem) {

    const int*   qe = q + (size_t)e * (K/8) * N;
    const float* se = s + (size_t)e * NG * N;
    const int*   ge = g + (size_t)e * K + k0;
    __bf16*      oe = outw + (size_t)e * R * K;

    __bf16 (*tile)[128] = reinterpret_cast<__bf16(*)[128]>(smem);

    const int t  = threadIdx.x;
    const int rl = t & 63, kq = t >> 6;
    const int r  = r0 + rl;
    const int S  = INTERLEAVE ? (((r >> 4) << 3) + (r & 7) + (((r >> 3) & 1) ? (N >> 1) : 0))
                              : r;
    #pragma unroll
    for (int jj = 0; jj < 4; jj++) {
        int kp = kq + jj*4;
        int qv = qe[(size_t)(k0/8 + kp) * N + S];
        __align__(16) __bf16 tmp[8];
        #pragma unroll
        for (int j2 = 0; j2 < 8; j2++) {
            float sc = se[(size_t)ge[kp*8 + j2] * N + S];
            tmp[j2] = (__bf16)((float)(((qv >> (4*j2)) & 15) - 8) * sc);
        }
        int c = kp ^ (rl & 15);
        *reinterpret_cast<f32x4*>(&tile[rl][c*8]) = *reinterpret_cast<f32x4*>(tmp);
    }
    __syncthreads();
    #pragma unroll
    for (int i = 0; i < 4; i++) {
        int sidx = t + i*256;
        int row = sidx >> 4, ch = sidx & 15;
        int cs = ch ^ (row & 15);
        *reinterpret_cast<f32x4*>(oe + (size_t)(r0+row)*K + k0 + ch*8)
            = *reinterpret_cast<const f32x4*>(&tile[row][cs*8]);
    }
}

__global__ __launch_bounds__(256) void k_prep(
    const int* __restrict__ w13q, const float* __restrict__ w13s, const int* __restrict__ g13,
    const int* __restrict__ w2q,  const float* __restrict__ w2s,  const int* __restrict__ g2,
    __bf16* __restrict__ B1t, __bf16* __restrict__ W2t,
    const float* __restrict__ logits,
    int* __restrict__ offs, int* __restrict__ plist, float* __restrict__ pw,
    int* __restrict__ spos, int* __restrict__ wl, int* __restrict__ nts) {

    __shared__ __align__(16) char smem[24704];
    int bid = blockIdx.x;

    if (bid == 0) {
        // ---- routing: top-2 + count + scan + scatter + 128-row worklist
        int*   cnt = reinterpret_cast<int*>(smem);              // 8 ints
        int*   cur = cnt + NEXP;                                // 8 ints
        short* se2 = reinterpret_cast<short*>(cnt + 2*NEXP);    // 2*T_TOK shorts
        float* swt = reinterpret_cast<float*>(se2 + 2*T_TOK);   // 2*T_TOK floats

        const int tid = threadIdx.x;
        if (tid < NEXP) cnt[tid] = 0;
        __syncthreads();

        for (int t = tid; t < T_TOK; t += 256) {
            float l[NEXP];
            #pragma unroll
            for (int e = 0; e < NEXP; e++) l[e] = logits[t * NEXP + e];
            int i0 = 0; float b0 = l[0];
            #pragma unroll
            for (int e = 1; e < NEXP; e++) if (l[e] > b0) { b0 = l[e]; i0 = e; }
            int i1 = -1; float b1 = -1e30f;
            #pragma unroll
            for (int e = 0; e < NEXP; e++) if (e != i0 && l[e] > b1) { b1 = l[e]; i1 = e; }
            float w1 = 1.f / (1.f + __expf(b0 - b1));
            float w0 = 1.f - w1;
            se2[2*t] = (short)i0; se2[2*t+1] = (short)i1;
            swt[2*t] = w0; swt[2*t+1] = w1;
            atomicAdd(&cnt[i0], 1);
            atomicAdd(&cnt[i1], 1);
        }
        __syncthreads();

        if (tid == 0) {
            int s = 0;
            for (int e = 0; e < NEXP; e++) { offs[e] = s; cur[e] = s; s += cnt[e]; }
            offs[NEXP] = s;
            int n = 0;
            for (int e = 0; e < NEXP; e++)
                for (int mt = 0; mt * 128 < cnt[e]; mt++) wl[n++] = (e << 8) | mt;
            nts[0] = n;
        }
        __syncthreads();

        for (int t = tid; t < T_TOK; t += 256) {
            #pragma unroll
            for (int s = 0; s < 2; s++) {
                int e = se2[2*t+s];
                int pos = atomicAdd(&cur[e], 1);
                plist[pos] = t;
                pw[pos] = swt[2*t+s];
                spos[2*t+s] = pos;
            }
        }
        return;
    }
    bid -= 1;
    if (bid < DQ1_BLOCKS) {
        // dequant13: grid (128, 8, 8) linearized
        const int x = bid & 127, y = (bid >> 7) & 7, e = bid >> 10;
        dequant_tile<true>(w13q, w13s, g13, B1t, N13, H_DIM, N13, NG13,
                           e, x * 64, y * 128, smem);
        return;
    }
    bid -= DQ1_BLOCKS;
    {
        // dequant2: grid (16, 32, 8) linearized
        const int x = bid & 15, y = (bid >> 4) & 31, e = bid >> 9;
        dequant_tile<false>(w2q, w2s, g2, W2t, N2, I_DIM, N2, NG2,
                            e, x * 64, y * 128, smem);
    }
}

__global__ void k_gather(const float* __restrict__ x, const int* __restrict__ plist,
                         __bf16* __restrict__ xg) {
    int p = blockIdx.x;
    int t = plist[p];
    int i = threadIdx.x;
    const f32x4* src = reinterpret_cast<const f32x4*>(x + (size_t)t * H_DIM);
    f32x4 v0 = src[i*2], v1 = src[i*2+1];
    __align__(16) __bf16 tb[8];
    #pragma unroll
    for (int j = 0; j < 4; j++) { tb[j] = (__bf16)v0[j]; tb[4+j] = (__bf16)v1[j]; }
    *reinterpret_cast<f32x4*>(xg + (size_t)p * H_DIM + i*8) = *reinterpret_cast<f32x4*>(tb);
}

// =====================================================================
// 8-phase GEMM cores (round-7-verified), both 128x256 tile, 2 phases/
// K-tile, counted VM3, raw barriers, worklist-driven.
// =====================================================================
#define VM3 asm volatile("s_waitcnt vmcnt(3)" ::: "memory")
#define VM0 asm volatile("s_waitcnt vmcnt(0)" ::: "memory")
#define LGK0 { asm volatile("s_waitcnt lgkmcnt(0)" ::: "memory"); __builtin_amdgcn_sched_barrier(0); }
#define BARRIER  { __builtin_amdgcn_s_barrier(); __builtin_amdgcn_sched_barrier(0); }
#define SCHEDFENCE __builtin_amdgcn_sched_barrier(0)

// ---------------- gemm1: 128x256 tile, K=1024 ----------------
__global__ __launch_bounds__(512) void k_gemm1(
    const __bf16* __restrict__ xg,
    const __bf16* __restrict__ B1t,
    const int*    __restrict__ offs,
    const float*  __restrict__ pw,
    const int*    __restrict__ wl,
    const int*    __restrict__ nts,
    __bf16*       __restrict__ act) {

    const int ti = blockIdx.x >> 5;        // 32 nb per tile
    if (ti >= nts[0]) return;
    const int nb = blockIdx.x & 31;
    const int w  = wl[ti];
    const int e  = w >> 8, mt = w & 255;
    const int m0 = offs[e] + mt * 128;
    const int mcount = min(offs[e+1] - m0, 128);
    const int n0r = nb * 256;

    __shared__ __align__(16) __bf16 AsF[2*2*4096];   // [parity][khalf][128*32]
    __shared__ __align__(16) __bf16 BsF[2*2*8192];   // [parity][khalf][256*32]
    __shared__ float wts[128];

    const int tid = threadIdx.x;
    const int wv = tid >> 6, lane = tid & 63;
    const int lrow = lane & 15, quad = lane >> 4;
    const int wr = (wv >> 2) * 64;       // 2 M-waves x 64 rows
    const int wc = (wv & 3) * 64;        // 4 N-waves x 64 cols
    const int cq = quad ^ ((lrow >> 1) & 3);

    for (int m = tid; m < 128; m += 512)
        wts[m] = (m < mcount) ? pw[m0 + m] : 0.f;

    const __bf16* Abase = xg  + (size_t)m0 * H_DIM;
    const __bf16* Bbase = B1t + ((size_t)e * N13 + n0r) * H_DIM;

    f32x4 acc[4][4];
    #pragma unroll
    for (int i = 0; i < 4; i++)
        #pragma unroll
        for (int j = 0; j < 4; j++) acc[i][j] = (f32x4)(0.f);

    auto stageA = [&](int prt, int h2, int kt) {   // 1 load/thread
        const __bf16* g = Abase + kt * BK + h2 * 32;
        __bf16* d = AsF + prt * 8192 + h2 * 4096;
        int row = tid >> 2;
        int gch = (tid & 3) ^ ((row >> 1) & 3);
        int rowc = min(row, mcount - 1);
        GLD_LDS(g + (size_t)rowc * H_DIM + gch * 8, d + tid * 8);
    };
    auto stageB = [&](int prt, int h2, int kt) {   // 2 loads/thread
        const __bf16* g = Bbase + kt * BK + h2 * 32;
        __bf16* d = BsF + prt * 16384 + h2 * 8192;
        #pragma unroll
        for (int q2 = 0; q2 < 2; q2++) {
            int row = (tid >> 2) + q2 * 128;
            int gch = (tid & 3) ^ ((row >> 1) & 3);
            GLD_LDS(g + (size_t)row * H_DIM + gch * 8, d + tid * 8 + q2 * 4096);
        }
    };

    stageA(0, 0, 0); stageB(0, 0, 0); stageA(0, 1, 0); stageB(0, 1, 0);

    const int NT = H_DIM / BK;   // 16
    for (int kt = 0; kt < NT; kt++) {
        const int prt = kt & 1, nxt = prt ^ 1;
        const bool st = (kt + 1 < NT);
        const __bf16* Ab = AsF + prt * 8192;
        const __bf16* Bb = BsF + prt * 16384;
        #pragma unroll
        for (int h2 = 0; h2 < 2; h2++) {
            if (h2 == 0) { VM3; } else if (st) { VM3; } else { VM0; }
            BARRIER;
            {
                bf16x8 bb[4], a[4];
                #pragma unroll
                for (int j = 0; j < 4; j++)
                    bb[j] = *reinterpret_cast<const bf16x8*>(
                        &Bb[h2*8192 + (wc + 16*j + lrow)*32 + cq*8]);
                #pragma unroll
                for (int i = 0; i < 4; i++)
                    a[i] = *reinterpret_cast<const bf16x8*>(
                        &Ab[h2*4096 + (wr + 16*i + lrow)*32 + cq*8]);
                if (st) { stageA(nxt, h2, kt + 1); stageB(nxt, h2, kt + 1); }
                LGK0;
                __builtin_amdgcn_s_setprio(1);
                #pragma unroll
                for (int j = 0; j < 4; j++)
                    #pragma unroll
                    for (int i = 0; i < 4; i++)
                        acc[i][j] = __builtin_amdgcn_mfma_f32_16x16x32_bf16(a[i], bb[j], acc[i][j], 0, 0, 0);
                __builtin_amdgcn_s_setprio(0);
            }
            SCHEDFENCE;
        }
    }

    // epilogue: lrow<8 = gate, lrow>=8 = up of same logical col (shfl pair)
    #pragma unroll
    for (int j = 0; j < 4; j++) {
        const int c0 = ((n0r + wc + 16*j) >> 1);
        #pragma unroll
        for (int i = 0; i < 4; i++)
            #pragma unroll
            for (int rr = 0; rr < 4; rr++) {
                float v = acc[i][j][rr];
                float partner = __shfl_xor(v, 8, 64);
                int m = wr + 16*i + quad*4 + rr;
                if (lrow < 8 && m < mcount) {
                    float gg = v, uu = partner;
                    float a = (gg / (1.f + __expf(-gg))) * uu * wts[m];
                    act[(size_t)(m0 + m) * I_DIM + c0 + lrow] = (__bf16)a;
                }
            }
    }
}

// ---------------- gemm2: 128x256 tile, K=1024 (KSPLIT2=4), NO atomics ----
__global__ __launch_bounds__(512) void k_gemm2(
    const __bf16* __restrict__ act,
    const __bf16* __restrict__ W2t,
    const int*    __restrict__ offs,
    const int*    __restrict__ wl,
    const int*    __restrict__ nts,
    float*        __restrict__ outp) {

    const int ti = blockIdx.x >> 4;        // 4 nb * 4 ks per tile
    if (ti >= nts[0]) return;
    const int nb = (blockIdx.x >> 2) & 3;
    const int ks = blockIdx.x & 3;
    const int w  = wl[ti];
    const int e  = w >> 8, mt = w & 255;
    const int m0 = offs[e] + mt * 128;
    const int mcount = min(offs[e+1] - m0, 128);
    const int n0 = nb * 256;
    const int kz = ks * KLEN2;

    __shared__ __align__(16) __bf16 AsF[2*2*4096];   // [parity][khalf][128*32]
    __shared__ __align__(16) __bf16 BsF[2*2*8192];   // [parity][khalf][256*32]

    const int tid = threadIdx.x;
    const int wv = tid >> 6, lane = tid & 63;
    const int lrow = lane & 15, quad = lane >> 4;
    const int wr = (wv >> 2) * 64;
    const int wc = (wv & 3) * 64;
    const int cq = quad ^ ((lrow >> 1) & 3);

    const __bf16* Abase = act + (size_t)m0 * I_DIM + kz;
    const __bf16* Bbase = W2t + ((size_t)e * N2 + n0) * I_DIM + kz;

    f32x4 acc[4][4];
    #pragma unroll
    for (int i = 0; i < 4; i++)
        #pragma unroll
        for (int j = 0; j < 4; j++) acc[i][j] = (f32x4)(0.f);

    auto stageA = [&](int prt, int h2, int kt) {   // 1 load/thread
        const __bf16* g = Abase + kt * BK + h2 * 32;
        __bf16* d = AsF + prt * 8192 + h2 * 4096;
        int row = tid >> 2;
        int gch = (tid & 3) ^ ((row >> 1) & 3);
        int rowc = min(row, mcount - 1);
        GLD_LDS(g + (size_t)rowc * I_DIM + gch * 8, d + tid * 8);
    };
    auto stageB = [&](int prt, int h2, int kt) {   // 2 loads/thread
        const __bf16* g = Bbase + kt * BK + h2 * 32;
        __bf16* d = BsF + prt * 16384 + h2 * 8192;
        #pragma unroll
        for (int q2 = 0; q2 < 2; q2++) {
            int row = (tid >> 2) + q2 * 128;
            int gch = (tid & 3) ^ ((row >> 1) & 3);
            GLD_LDS(g + (size_t)row * I_DIM + gch * 8, d + tid * 8 + q2 * 4096);
        }
    };

    stageA(0, 0, 0); stageB(0, 0, 0); stageA(0, 1, 0); stageB(0, 1, 0);

    const int NT = KLEN2 / BK;   // 16
    for (int kt = 0; kt < NT; kt++) {
        const int prt = kt & 1, nxt = prt ^ 1;
        const bool st = (kt + 1 < NT);
        const __bf16* Ab = AsF + prt * 8192;
        const __bf16* Bb = BsF + prt * 16384;
        #pragma unroll
        for (int h2 = 0; h2 < 2; h2++) {
            if (h2 == 0) { VM3; } else if (st) { VM3; } else { VM0; }
            BARRIER;
            {
                bf16x8 bb[4], a[4];
                #pragma unroll
                for (int j = 0; j < 4; j++)
                    bb[j] = *reinterpret_cast<const bf16x8*>(
                        &Bb[h2*8192 + (wc + 16*j + lrow)*32 + cq*8]);
                #pragma unroll
                for (int i = 0; i < 4; i++)
                    a[i] = *reinterpret_cast<const bf16x8*>(
                        &Ab[h2*4096 + (wr + 16*i + lrow)*32 + cq*8]);
                if (st) { stageA(nxt, h2, kt + 1); stageB(nxt, h2, kt + 1); }
                LGK0;
                __builtin_amdgcn_s_setprio(1);
                #pragma unroll
                for (int j = 0; j < 4; j++)
                    #pragma unroll
                    for (int i = 0; i < 4; i++)
                        acc[i][j] = __builtin_amdgcn_mfma_f32_16x16x32_bf16(a[i], bb[j], acc[i][j], 0, 0, 0);
                __builtin_amdgcn_s_setprio(0);
            }
            SCHEDFENCE;
        }
    }

    // plain stores to pair-slot partial buffer (no conflicts: unique (ks,p,h))
    float* op = outp + ((size_t)ks * PAIR_PAD + m0) * N2;
    #pragma unroll
    for (int j = 0; j < 4; j++) {
        int h = n0 + wc + 16*j + lrow;
        #pragma unroll
        for (int i = 0; i < 4; i++)
            #pragma unroll
            for (int rr = 0; rr < 4; rr++) {
                int m = wr + 16*i + quad*4 + rr;
                if (m < mcount)
                    op[(size_t)m * N2 + h] = acc[i][j][rr];
            }
    }
}

// ---------------- final reduce: out[t] = sum over 2 slots x KSPLIT2 ----
__global__ __launch_bounds__(256) void k_reduce(
    const float* __restrict__ outp, const int* __restrict__ spos,
    float* __restrict__ out) {
    const int t  = blockIdx.x;
    const int h4 = threadIdx.x;            // 256 threads x float4 = 1024 h
    const int p0 = spos[2*t], p1 = spos[2*t+1];
    const f32x4* r0 = reinterpret_cast<const f32x4*>(outp + (size_t)p0 * H_DIM) + h4;
    const f32x4* r1 = reinterpret_cast<const f32x4*>(outp + (size_t)p1 * H_DIM) + h4;
    f32x4 acc = (f32x4)(0.f);
    #pragma unroll
    for (int ks = 0; ks < KSPLIT2; ks++) {
        size_t off = (size_t)ks * (PAIR_PAD * (H_DIM/4));
        acc += r0[off] + r1[off];
    }
    reinterpret_cast<f32x4*>(out + (size_t)t * H_DIM)[h4] = acc;
}

// =====================================================================
extern "C" void kernel_launch(void* const* d_in, const int* in_sizes, int n_in,
                              void* d_out, int out_size, void* d_ws, size_t ws_size,
                              hipStream_t stream) {
    const float* x      = (const float*)d_in[0];
    const float* logits = (const float*)d_in[1];
    const int*   w13q   = (const int*)  d_in[2];
    const int*   w2q    = (const int*)  d_in[3];
    const float* w13s   = (const float*)d_in[4];
    const float* w2s    = (const float*)d_in[5];
    const int*   g13    = (const int*)  d_in[6];
    const int*   g2     = (const int*)  d_in[7];

    char* ws = (char*)d_ws;
    int*    offs   = (int*)   (ws + WS_OFFS);
    int*    plist  = (int*)   (ws + WS_PLIST);
    float*  pw     = (float*) (ws + WS_PW);
    int*    wl     = (int*)   (ws + WS_WL);
    int*    nts    = (int*)   (ws + WS_NTS);
    int*    spos   = (int*)   (ws + WS_SPOS);
    __bf16* xg     = (__bf16*)(ws + WS_XG);
    __bf16* act    = (__bf16*)(ws + WS_ACT);
    __bf16* B1t    = (__bf16*)(ws + WS_B1T);
    __bf16* W2t    = (__bf16*)(ws + WS_W2T);
    float*  outp   = (float*) (ws + WS_B1T);   // aliases B1t (dead after gemm1)
    float*  out    = (float*) d_out;

    // one launch: route (block 0) + dequant13 + dequant2
    k_prep<<<1 + DQ1_BLOCKS + DQ2_BLOCKS, 256, 0, stream>>>(
        w13q, w13s, g13, w2q, w2s, g2, B1t, W2t,
        logits, offs, plist, pw, spos, wl, nts);

    k_gather<<<2*T_TOK, 128, 0, stream>>>(x, plist, xg);

    // worklist-driven grids: 128-row tiles x fan-out
    k_gemm1<<<MAXT2 * 32, 512, 0, stream>>>(xg, B1t, offs, pw, wl, nts, act);
    k_gemm2<<<MAXT2 * 16, 512, 0, stream>>>(act, W2t, offs, wl, nts, outp);
    k_reduce<<<T_TOK, 256, 0, stream>>>(outp, spos, out);
}